// Round 2
// baseline (499.670 us; speedup 1.0000x reference)
//
#include <hip/hip_runtime.h>

#define NN 512
#define CCH 128
#define MM (NN*NN)   // 262144

using f32x4  = __attribute__((ext_vector_type(4))) float;
using f32x2  = __attribute__((ext_vector_type(2))) float;
using bf16x8 = __attribute__((ext_vector_type(8))) short;
using u16x4  = __attribute__((ext_vector_type(4))) unsigned short;
typedef unsigned short u16;

__device__ __forceinline__ u16 f2bf(float f) {
    unsigned u = __builtin_bit_cast(unsigned, f);
    u += 0x7FFF + ((u >> 16) & 1);
    return (u16)(u >> 16);
}
__device__ __forceinline__ float bf2f(u16 h) {
    unsigned u = ((unsigned)h) << 16;
    return __builtin_bit_cast(float, u);
}
__device__ __forceinline__ float sigm(float x) { return 1.0f / (1.0f + __expf(-x)); }

__device__ __forceinline__ void gl_lds16(const void* g, void* l) {
    __builtin_amdgcn_global_load_lds(
        (const __attribute__((address_space(1))) void*)g,
        (__attribute__((address_space(3))) void*)l, 16, 0, 0);
}

// ---------------- k_prep: fold LN gamma/beta into bf16 weights + biases ----
// wbf[mat][o][c] = bf16(W[o][c] * gamma[c]);  bias2[mat][o] = b[o] + sum_c beta[c]*W[o][c]
// mats: 0=ag 1=ap 2=bg 3=bp 4=g (gamma_in/beta_in), 5=z (gamma_out/beta_out)
__global__ __launch_bounds__(256) void k_prep(
    const float* __restrict__ w0, const float* __restrict__ w1,
    const float* __restrict__ w2, const float* __restrict__ w3,
    const float* __restrict__ w4, const float* __restrict__ w5,
    const float* __restrict__ b0, const float* __restrict__ b1,
    const float* __restrict__ b2, const float* __restrict__ b3,
    const float* __restrict__ b4, const float* __restrict__ b5,
    const float* __restrict__ gin, const float* __restrict__ bin,
    const float* __restrict__ gout, const float* __restrict__ bout,
    u16* __restrict__ wbf, float* __restrict__ bias2) {
    int mat = blockIdx.x;
    const float* W = mat==0?w0:mat==1?w1:mat==2?w2:mat==3?w3:mat==4?w4:w5;
    const float* B = mat==0?b0:mat==1?b1:mat==2?b2:mat==3?b3:mat==4?b4:b5;
    const float* G = (mat==5)? gout : gin;
    const float* Bt= (mat==5)? bout : bin;
    __shared__ float gs[CCH], bs[CCH];
    int tid = threadIdx.x;
    if (tid < CCH) { gs[tid] = G[tid]; bs[tid] = Bt[tid]; }
    __syncthreads();
    int o = tid >> 1, c0 = (tid & 1) * 64;
    const float* src = W + o * CCH + c0;
    u16* dst = wbf + mat * 16384 + o * CCH + c0;
    float dot = 0.f;
    #pragma unroll
    for (int q = 0; q < 16; ++q) {
        f32x4 v = *(const f32x4*)(src + q * 4);
        int c = c0 + q * 4;
        dot += bs[c]*v.x + bs[c+1]*v.y + bs[c+2]*v.z + bs[c+3]*v.w;
        u16x4 p;
        p.x = f2bf(v.x * gs[c]);     p.y = f2bf(v.y * gs[c+1]);
        p.z = f2bf(v.z * gs[c+2]);   p.w = f2bf(v.w * gs[c+3]);
        *(u16x4*)(dst + q * 4) = p;
    }
    dot += __shfl_xor(dot, 1);
    if ((tid & 1) == 0) bias2[mat * CCH + o] = B[o] + dot;
}

// ---------------- k_projLN: LN(z) + 5 projections, fused -------------------
// per block: 128 rows. LN in-block -> bf16 tile in LDS -> MFMA vs global bf16
// weights. Outputs: aT[c][m], bT[c][m] (transposed via LDS), gate -> head of
// each d_out row (bf16 sigm value), row m at bytes [m*512, m*512+256).
__global__ __launch_bounds__(256) void k_projLN(
    const float* __restrict__ z, const float* __restrict__ mask,
    const u16* __restrict__ wbf, const float* __restrict__ bias2,
    u16* __restrict__ aT, u16* __restrict__ bT, u16* gateB) {
    __shared__ __align__(16) u16 tb[128 * 128];   // 32KB
    int tid = threadIdx.x, w = tid >> 6, lane = tid & 63;
    int r = lane & 15, kq = lane >> 4;
    long m0 = (long)blockIdx.x * 128;

    // --- LN stage: 2 threads per row ---
    {
        int row = tid >> 1, c0 = (tid & 1) * 64;
        const float* zr = z + (m0 + row) * CCH + c0;
        f32x4 va[16];
        float s = 0.f, s2 = 0.f;
        #pragma unroll
        for (int q = 0; q < 16; ++q) {
            va[q] = *(const f32x4*)(zr + q * 4);
            s  += va[q].x + va[q].y + va[q].z + va[q].w;
            s2 += va[q].x*va[q].x + va[q].y*va[q].y + va[q].z*va[q].z + va[q].w*va[q].w;
        }
        s += __shfl_xor(s, 1); s2 += __shfl_xor(s2, 1);
        float mu = s * (1.0f / CCH);
        float var = s2 * (1.0f / CCH) - mu * mu;
        float rs = rsqrtf(var + 1e-5f);
        int sw = (row & 15) << 4;
        #pragma unroll
        for (int q2 = 0; q2 < 8; ++q2) {   // 16B chunks: 8 bf16 each
            u16x4 pa, pb;
            f32x4 v0 = va[q2*2], v1 = va[q2*2+1];
            pa.x = f2bf((v0.x-mu)*rs); pa.y = f2bf((v0.y-mu)*rs);
            pa.z = f2bf((v0.z-mu)*rs); pa.w = f2bf((v0.w-mu)*rs);
            pb.x = f2bf((v1.x-mu)*rs); pb.y = f2bf((v1.y-mu)*rs);
            pb.z = f2bf((v1.z-mu)*rs); pb.w = f2bf((v1.w-mu)*rs);
            char* p = (char*)tb + row * 256 + ((c0 * 2 + q2 * 16) ^ sw);
            *(u16x4*)p = pa;
            *(u16x4*)(p + 8) = pb;
        }
    }
    __syncthreads();

    // --- A-fragments from LDS (2 m-tiles per wave) ---
    bf16x8 av[2][4];
    #pragma unroll
    for (int mt = 0; mt < 2; ++mt) {
        int row = w * 32 + mt * 16 + r;
        int sw = (row & 15) << 4;
        #pragma unroll
        for (int kb = 0; kb < 4; ++kb)
            av[mt][kb] = *(const bf16x8*)((const char*)tb + row * 256 + ((kb * 64 + kq * 16) ^ sw));
    }
    float mk[2][4];
    #pragma unroll
    for (int mt = 0; mt < 2; ++mt)
        #pragma unroll
        for (int j = 0; j < 4; ++j)
            mk[mt][j] = mask[m0 + w * 32 + mt * 16 + kq * 4 + j];

    // --- phases 0,1: gated pair-GEMMs -> aT / bT ---
    #pragma unroll 1
    for (int ph = 0; ph < 2; ++ph) {
        const u16* W1 = wbf + (ph * 2 + 0) * 16384;
        const u16* W2 = wbf + (ph * 2 + 1) * 16384;
        const float* B1 = bias2 + (ph * 2 + 0) * CCH;
        const float* B2 = bias2 + (ph * 2 + 1) * CCH;
        f32x4 a1[2][8], a2[2][8];
        #pragma unroll
        for (int mt = 0; mt < 2; ++mt)
            #pragma unroll
            for (int nt = 0; nt < 8; ++nt) { a1[mt][nt] = {0,0,0,0}; a2[mt][nt] = {0,0,0,0}; }
        #pragma unroll
        for (int nt = 0; nt < 8; ++nt) {
            #pragma unroll
            for (int kb = 0; kb < 4; ++kb) {
                int off = (nt * 16 + r) * CCH + kb * 32 + kq * 8;
                bf16x8 bw1 = *(const bf16x8*)(W1 + off);
                bf16x8 bw2 = *(const bf16x8*)(W2 + off);
                a1[0][nt] = __builtin_amdgcn_mfma_f32_16x16x32_bf16(av[0][kb], bw1, a1[0][nt], 0, 0, 0);
                a1[1][nt] = __builtin_amdgcn_mfma_f32_16x16x32_bf16(av[1][kb], bw1, a1[1][nt], 0, 0, 0);
                a2[0][nt] = __builtin_amdgcn_mfma_f32_16x16x32_bf16(av[0][kb], bw2, a2[0][nt], 0, 0, 0);
                a2[1][nt] = __builtin_amdgcn_mfma_f32_16x16x32_bf16(av[1][kb], bw2, a2[1][nt], 0, 0, 0);
            }
        }
        __syncthreads();   // prior tb readers done (av reads / prev phase readout)
        #pragma unroll
        for (int nt = 0; nt < 8; ++nt) {
            int cc = nt * 16 + r;
            float b1v = B1[cc], b2v = B2[cc];
            int sw = (cc & 15) << 4;
            #pragma unroll
            for (int mt = 0; mt < 2; ++mt) {
                u16x4 p;
                #pragma unroll
                for (int j = 0; j < 4; ++j) {
                    float val = mk[mt][j] * sigm(a1[mt][nt][j] + b1v) * (a2[mt][nt][j] + b2v);
                    p[j] = f2bf(val);
                }
                int ml0 = w * 32 + mt * 16 + kq * 4;
                *(u16x4*)((char*)tb + cc * 256 + ((ml0 * 2) ^ sw)) = p;
            }
        }
        __syncthreads();
        u16* dst = ph ? bT : aT;
        int c = tid >> 1, half = tid & 1, swc = (c & 15) << 4;
        long gb = (long)c * MM + m0 + half * 64;
        #pragma unroll
        for (int qq = 0; qq < 8; ++qq) {
            bf16x8 vv = *(const bf16x8*)((const char*)tb + c * 256 + ((half * 128 + qq * 16) ^ swc));
            *(bf16x8*)(dst + gb + qq * 8) = vv;
        }
    }

    // --- gate phase: sigm(zn @ w_g'^T + b2_g) -> d_out row heads (bf16) ---
    {
        const u16* Wg = wbf + 4 * 16384;
        f32x4 g[2][8];
        #pragma unroll
        for (int mt = 0; mt < 2; ++mt)
            #pragma unroll
            for (int nt = 0; nt < 8; ++nt) g[mt][nt] = {0,0,0,0};
        #pragma unroll
        for (int nt = 0; nt < 8; ++nt) {
            #pragma unroll
            for (int kb = 0; kb < 4; ++kb) {
                int off = (nt * 16 + r) * CCH + kb * 32 + kq * 8;
                bf16x8 bw = *(const bf16x8*)(Wg + off);
                g[0][nt] = __builtin_amdgcn_mfma_f32_16x16x32_bf16(av[0][kb], bw, g[0][nt], 0, 0, 0);
                g[1][nt] = __builtin_amdgcn_mfma_f32_16x16x32_bf16(av[1][kb], bw, g[1][nt], 0, 0, 0);
            }
        }
        #pragma unroll
        for (int nt = 0; nt < 8; ++nt) {
            int cc = nt * 16 + r;
            float bgv = bias2[4 * CCH + cc];
            #pragma unroll
            for (int mt = 0; mt < 2; ++mt)
                #pragma unroll
                for (int j = 0; j < 4; ++j) {
                    long m = m0 + w * 32 + mt * 16 + kq * 4 + j;
                    gateB[m * 256 + cc] = f2bf(sigm(g[mt][nt][j] + bgv));
                }
        }
    }
}

// ---------------- k_tri: per-channel triangle GEMM -------------------------
// xT[c][i*512+j] = sum_k aT[c][i*512+k] * bT[c][j*512+k]
__global__ __launch_bounds__(256) void k_tri(const u16* __restrict__ aT,
                                             const u16* __restrict__ bT,
                                             u16* __restrict__ xT) {
    __shared__ __align__(16) u16 At[128 * 32];
    __shared__ __align__(16) u16 Bt[128 * 32];
    int tid = threadIdx.x;
    int w = tid >> 6, lane = tid & 63;
    int c  = blockIdx.y;
    int ti = blockIdx.x >> 2, tj = blockIdx.x & 3;
    const char* abase = (const char*)(aT + (long)c * MM) + (long)(ti * 128) * 1024;
    const char* bbase = (const char*)(bT + (long)c * MM) + (long)(tj * 128) * 1024;
    int wm = w >> 1, wn = w & 1;
    int row4 = tid >> 2;
    int ko   = (tid & 3) * 16;

    f32x4 acc[4][4];
    #pragma unroll
    for (int a = 0; a < 4; ++a)
        #pragma unroll
        for (int bq = 0; bq < 4; ++bq) acc[a][bq] = {0.f,0.f,0.f,0.f};

    for (int ks = 0; ks < 16; ++ks) {
        int kb = ks * 64;
        gl_lds16(abase + (long)row4 * 1024 + kb + ko,        (char*)At + w * 1024);
        gl_lds16(abase + (long)(64 + row4) * 1024 + kb + ko, (char*)At + 4096 + w * 1024);
        gl_lds16(bbase + (long)row4 * 1024 + kb + ko,        (char*)Bt + w * 1024);
        gl_lds16(bbase + (long)(64 + row4) * 1024 + kb + ko, (char*)Bt + 4096 + w * 1024);
        __syncthreads();

        bf16x8 af[4];
        #pragma unroll
        for (int mt = 0; mt < 4; ++mt) {
            int rowa = wm * 64 + mt * 16 + (lane & 15);
            af[mt] = *(const bf16x8*)((const char*)At + rowa * 64 + (lane >> 4) * 16);
        }
        #pragma unroll
        for (int nt = 0; nt < 4; ++nt) {
            int rowb = wn * 64 + nt * 16 + (lane & 15);
            bf16x8 bf = *(const bf16x8*)((const char*)Bt + rowb * 64 + (lane >> 4) * 16);
            #pragma unroll
            for (int mt = 0; mt < 4; ++mt)
                acc[mt][nt] = __builtin_amdgcn_mfma_f32_16x16x32_bf16(af[mt], bf, acc[mt][nt], 0, 0, 0);
        }
        __syncthreads();
    }

    u16* xbase = xT + (long)c * MM;
    int gi0 = ti * 128 + wm * 64;
    int gj0 = tj * 128 + wn * 64 + (lane & 15);
    #pragma unroll
    for (int mt = 0; mt < 4; ++mt)
        #pragma unroll
        for (int nt = 0; nt < 4; ++nt)
            #pragma unroll
            for (int j = 0; j < 4; ++j) {
                long gi = gi0 + mt * 16 + (lane >> 4) * 4 + j;
                xbase[gi * NN + gj0 + nt * 16] = f2bf(acc[mt][nt][j]);
            }
}

// ---------------- k_out: LN(x) @ w_z''^T + bias2_z, * gate -----------------
__global__ __launch_bounds__(256) void k_out(const u16* __restrict__ xT,
                                             const u16* __restrict__ wbf,
                                             const float* __restrict__ bias2,
                                             const u16* gateB,
                                             float* outp) {
    __shared__ __align__(16) u16 xl[64 * 128];  // 16KB
    int tid = threadIdx.x, w = tid >> 6, lane = tid & 63;
    int r = lane & 15, kq = lane >> 4;
    long m0 = (long)blockIdx.x * 64;

    // transpose stage: xT[c][m] -> xl[m][c] (swizzled)
    {
        int c = tid & 127, half = tid >> 7;
        const u16* src = xT + (long)c * MM + m0 + half * 32;
        #pragma unroll
        for (int qq = 0; qq < 4; ++qq) {
            bf16x8 vv = *(const bf16x8*)(src + qq * 8);
            #pragma unroll
            for (int e = 0; e < 8; ++e) {
                int m = half * 32 + qq * 8 + e;
                *(u16*)((char*)xl + m * 256 + ((c * 2) ^ ((m & 15) << 4))) = (u16)vv[e];
            }
        }
    }
    __syncthreads();

    // A-frags + LN stats in registers
    int mlr = w * 16 + r;
    int swm = (mlr & 15) << 4;
    bf16x8 av[4];
    float s = 0.f, s2 = 0.f;
    #pragma unroll
    for (int kb = 0; kb < 4; ++kb) {
        av[kb] = *(const bf16x8*)((const char*)xl + mlr * 256 + ((kb * 64 + kq * 16) ^ swm));
        #pragma unroll
        for (int e = 0; e < 8; ++e) {
            float f = bf2f((u16)av[kb][e]);
            s += f; s2 += f * f;
        }
    }
    s  += __shfl_xor(s, 16);  s  += __shfl_xor(s, 32);
    s2 += __shfl_xor(s2, 16); s2 += __shfl_xor(s2, 32);
    float mu = s * (1.0f / CCH);
    float var = s2 * (1.0f / CCH) - mu * mu;
    float rs = rsqrtf(var + 1e-5f);
    #pragma unroll
    for (int kb = 0; kb < 4; ++kb)
        #pragma unroll
        for (int e = 0; e < 8; ++e) {
            float f = (bf2f((u16)av[kb][e]) - mu) * rs;
            av[kb][e] = (short)f2bf(f);
        }

    // gate preload (gateB aliases outp rows — must read before stores)
    u16 gv[8][4];
    #pragma unroll
    for (int nt = 0; nt < 8; ++nt)
        #pragma unroll
        for (int j = 0; j < 4; ++j) {
            long m = m0 + w * 16 + kq * 4 + j;
            gv[nt][j] = gateB[m * 256 + nt * 16 + r];
        }

    // MFMA vs w_z''
    const u16* Wz = wbf + 5 * 16384;
    f32x4 acc[8];
    #pragma unroll
    for (int nt = 0; nt < 8; ++nt) acc[nt] = {0,0,0,0};
    #pragma unroll
    for (int nt = 0; nt < 8; ++nt) {
        #pragma unroll
        for (int kb = 0; kb < 4; ++kb) {
            bf16x8 bw = *(const bf16x8*)(Wz + (nt * 16 + r) * CCH + kb * 32 + kq * 8);
            acc[nt] = __builtin_amdgcn_mfma_f32_16x16x32_bf16(av[kb], bw, acc[nt], 0, 0, 0);
        }
    }

    asm volatile("" ::: "memory");   // keep gate loads above aliasing stores

    const float* b2z = bias2 + 5 * CCH;
    #pragma unroll
    for (int nt = 0; nt < 8; ++nt) {
        int cc = nt * 16 + r;
        float bb = b2z[cc];
        #pragma unroll
        for (int j = 0; j < 4; ++j) {
            long m = m0 + w * 16 + kq * 4 + j;
            outp[m * CCH + cc] = (acc[nt][j] + bb) * bf2f(gv[nt][j]);
        }
    }
}

extern "C" void kernel_launch(void* const* d_in, const int* in_sizes, int n_in,
                              void* d_out, int out_size, void* d_ws, size_t ws_size,
                              hipStream_t stream) {
    const float* z       = (const float*)d_in[0];
    const float* mask    = (const float*)d_in[1];
    const float* ln_in_g = (const float*)d_in[2];
    const float* ln_in_b = (const float*)d_in[3];
    const float* w_ag    = (const float*)d_in[4];
    const float* b_ag    = (const float*)d_in[5];
    const float* w_ap    = (const float*)d_in[6];
    const float* b_ap    = (const float*)d_in[7];
    const float* w_bg    = (const float*)d_in[8];
    const float* b_bg    = (const float*)d_in[9];
    const float* w_bp    = (const float*)d_in[10];
    const float* b_bp    = (const float*)d_in[11];
    const float* w_g     = (const float*)d_in[12];
    const float* b_g     = (const float*)d_in[13];
    const float* w_z     = (const float*)d_in[14];
    const float* b_z     = (const float*)d_in[15];
    const float* ln_o_g  = (const float*)d_in[16];
    const float* ln_o_b  = (const float*)d_in[17];
    float* out = (float*)d_out;

    char* ws = (char*)d_ws;
    const size_t SL = (size_t)MM * CCH * 2;  // 64MB per slot
    u16* xT   = (u16*)ws;                     // slot 0 (triangle output)
    u16* aT   = (u16*)(ws + SL);              // slot 1
    u16* bT   = (u16*)(ws + 2 * SL);          // slot 2
    u16* wbf  = (u16*)(ws + 3 * SL);          // 384KB bf16 weights (gamma-folded)
    float* b2 = (float*)(ws + 3 * SL + 6 * 16384 * 2);  // 3KB folded biases
    u16* gateB = (u16*)d_out;                 // gate lives in d_out row heads

    k_prep<<<6, 256, 0, stream>>>(w_ag, w_ap, w_bg, w_bp, w_g, w_z,
                                  b_ag, b_ap, b_bg, b_bp, b_g, b_z,
                                  ln_in_g, ln_in_b, ln_o_g, ln_o_b, wbf, b2);
    k_projLN<<<MM / 128, 256, 0, stream>>>(z, mask, wbf, b2, aT, bT, gateB);
    k_tri<<<dim3(16, 128), 256, 0, stream>>>(aT, bT, xT);
    k_out<<<MM / 64, 256, 0, stream>>>(xT, wbf, b2, gateB, out);
}